// Round 1
// baseline (1051.051 us; speedup 1.0000x reference)
//
#include <hip/hip_runtime.h>
#include <cstddef>
#include <cstdint>

#define N_NODES 10000
#define N_EDGES 160000

// ---- constants ----
#define RS8    0.35355339059327373f   // 1/sqrt(8)
#define RS32   0.17677669529663687f   // 1/sqrt(32)
#define RS96   0.10206207261596575f   // 1/sqrt(96)
#define RS128  0.08838834764831845f   // 1/sqrt(128)
#define RS3    0.5773502691896258f    // 1/sqrt(3)
#define SQ3_   1.7320508075688772f
#define SQ5_   2.23606797749979f
#define A_     0.18257418583505536f   // 1/sqrt(30)
#define B_     0.31622776601683794f   // 1/sqrt(10)
#define SILU_C_ 1.6765208f
#define CS_    0.3826834323650898f    // sin(pi/8)
#define CX_    0.9238795325112867f    // cos(pi/8)
#define QDEG   0.25f                  // 1/sqrt(16)

__global__ void zero_kernel(float4* __restrict__ p, int n4) {
  int i = blockIdx.x * blockDim.x + threadIdx.x;
  if (i < n4) p[i] = make_float4(0.f, 0.f, 0.f, 0.f);
}

// s[n][0:160], y[n][0:160]: scalar block (64) + vector block (32x3, u-major)
__global__ void node_pre(const float* __restrict__ xin, const float* __restrict__ attr,
                         const float* __restrict__ sc_w0, const float* __restrict__ sc_w1,
                         const float* __restrict__ l1_w0, const float* __restrict__ l1_w1,
                         float* __restrict__ s, float* __restrict__ y) {
  int idx = blockIdx.x * blockDim.x + threadIdx.x;
  int n = idx / 160, c = idx - n * 160;
  const float* xr = xin + (size_t)n * 160;
  float a = attr[n];
  float sv, yv;
  if (c < 64) {
    float s_ = 0.f, y_ = 0.f;
    #pragma unroll 8
    for (int u = 0; u < 64; ++u) {
      float x = xr[u];
      s_ += x * sc_w0[u * 64 + c];
      y_ += x * l1_w0[u * 64 + c];
    }
    sv = s_ * a * 0.125f; yv = y_ * a * 0.125f;
  } else {
    int t = c - 64; int v = t / 3, i = t - v * 3;
    float s_ = 0.f, y_ = 0.f;
    #pragma unroll 8
    for (int u = 0; u < 32; ++u) {
      float x = xr[64 + u * 3 + i];
      s_ += x * sc_w1[u * 32 + v];
      y_ += x * l1_w1[u * 32 + v];
    }
    sv = s_ * a * RS32; yv = y_ * a * RS32;
  }
  s[idx] = sv; y[idx] = yv;
}

// one wave per edge, 8 waves (=8 edges) per block; fc_w1 staged in LDS in two
// 32-row chunks (40KB) to avoid re-reading 80KB from L2 per edge.
__global__ __launch_bounds__(512) void edge_kernel(
    const float* __restrict__ y, const int* __restrict__ esrc,
    const int* __restrict__ edst, const float* __restrict__ eattr,
    const float* __restrict__ ele, const float* __restrict__ fc0,
    const float* __restrict__ fc1, float* __restrict__ agg) {
  __shared__ float sh_fc1[32 * 320];   // 40KB
  __shared__ float sh_h[8][64];        // 2KB
  __shared__ float sh_w[8][320];       // 10KB
  __shared__ float sh_y[8][160];       // 5KB
  int wid = threadIdx.x >> 6, lane = threadIdx.x & 63;
  int e = blockIdx.x * 8 + wid;        // grid sized exactly: 20000*8 = 160000
  int src = esrc[e], dst = edst[e];

  // h = silu(ele @ fc0 / sqrt8) * SILU_C   (one element per lane)
  {
    const float* el = ele + (size_t)e * 8;
    float acc = 0.f;
    #pragma unroll
    for (int k = 0; k < 8; ++k) acc += el[k] * fc0[k * 64 + lane];
    acc *= RS8;
    sh_h[wid][lane] = SILU_C_ * acc / (1.f + __expf(-acc));
  }
  // gather y[src] row into LDS
  {
    const float* yr = y + (size_t)src * 160;
    sh_y[wid][lane] = yr[lane];
    sh_y[wid][64 + lane] = yr[64 + lane];
    if (lane < 32) sh_y[wid][128 + lane] = yr[128 + lane];
  }

  // w = h @ fc1 / 8   (5 columns per lane, K split in 2 chunks of 32)
  float wacc[5] = {0.f, 0.f, 0.f, 0.f, 0.f};
  for (int chunk = 0; chunk < 2; ++chunk) {
    __syncthreads();
    const float4* srcf = (const float4*)(fc1 + (size_t)chunk * 32 * 320);
    float4* dstf = (float4*)sh_fc1;
    for (int i = threadIdx.x; i < 32 * 320 / 4; i += 512) dstf[i] = srcf[i];
    __syncthreads();
    #pragma unroll
    for (int j = 0; j < 5; ++j) {
      int c = lane + 64 * j;
      float a2 = 0.f;
      #pragma unroll
      for (int u = 0; u < 32; ++u)
        a2 += sh_h[wid][chunk * 32 + u] * sh_fc1[u * 320 + c];
      wacc[j] += a2;
    }
  }
  #pragma unroll
  for (int j = 0; j < 5; ++j) sh_w[wid][lane + 64 * j] = wacc[j] * 0.125f;
  __syncthreads();

  // edge spherical harmonics (wave-uniform scalar loads)
  const float* ea = eattr + (size_t)e * 9;
  float e0 = ea[0];
  float ey = ea[1], ez = ea[2], ex = ea[3];
  float g0 = ea[4], g1 = ea[5], g2 = ea[6], g3 = ea[7], g4 = ea[8];

  const float* Y0 = &sh_y[wid][0];
  const float* X1 = &sh_y[wid][64];
  const float* W  = &sh_w[wid][0];
  float* aggrow = agg + (size_t)dst * 960;

  // 960 outputs, 15 per lane; layout: [k0:64][k1:32][k2:192][k3:96][k4:96][k5:320][k6:160]
  #pragma unroll
  for (int j = 0; j < 15; ++j) {
    int c = lane + 64 * j;
    float val;
    if (c < 64) {
      val = Y0[c] * e0 * W[c];
    } else if (c < 96) {
      int u = c - 64;
      val = RS3 * (X1[u*3] * ey + X1[u*3+1] * ez + X1[u*3+2] * ex) * W[224 + u];
    } else if (c < 288) {
      int t = c - 96, u = t / 3, k = t - u * 3;
      float ek = (k == 0) ? ey : ((k == 1) ? ez : ex);
      val = Y0[u] * ek * W[64 + u];
    } else if (c < 384) {
      int t = c - 288, u = t / 3, k = t - u * 3;
      val = X1[u*3 + k] * e0 * W[192 + u];
    } else if (c < 480) {
      int t = c - 384, u = t / 3, k = t - u * 3;
      float xy = X1[u*3], xz = X1[u*3+1], xx = X1[u*3+2];
      float K;
      if (k == 0)      K = B_ * (xx * g0 + xz * g1 - xy * g4) - A_ * xy * g2;
      else if (k == 1) K = B_ * (xy * g1 + xx * g3) + 2.f * A_ * xz * g2;
      else             K = B_ * (xy * g0 + xz * g3 + xx * g4) - A_ * xx * g2;
      val = SQ3_ * W[288 + u] * K;
    } else if (c < 800) {
      int t = c - 480, u = t / 5, k = t - u * 5;
      float gk = (k == 0) ? g0 : ((k == 1) ? g1 : ((k == 2) ? g2 : ((k == 3) ? g3 : g4)));
      val = Y0[u] * gk * W[128 + u];
    } else {
      int t = c - 800, u = t / 5, k = t - u * 5;
      float xy = X1[u*3], xz = X1[u*3+1], xx = X1[u*3+2];
      float K;
      if (k == 0)      K = -B_ * (xy * ex + xx * ey);
      else if (k == 1) K = -B_ * (xy * ez + xz * ey);
      else if (k == 2) K =  A_ * (xy * ey + xx * ex - 2.f * xz * ez);
      else if (k == 3) K = -B_ * (xz * ex + xx * ez);
      else             K =  B_ * (xy * ey - xx * ex);
      val = SQ5_ * W[256 + u] * K;
    }
    unsafeAtomicAdd(aggrow + c, val * QDEG);
  }
}

// lin2 + combine: one block (320 threads) per node, agg row staged in LDS
__global__ __launch_bounds__(320) void node_post(
    const float* __restrict__ agg, const float* __restrict__ s,
    const float* __restrict__ attr, const float* __restrict__ w0,
    const float* __restrict__ w1, const float* __restrict__ w2,
    float* __restrict__ out) {
  __shared__ float sm[960];
  int n = blockIdx.x;
  const float* ar = agg + (size_t)n * 960;
  for (int i = threadIdx.x; i < 960; i += 320) sm[i] = ar[i];
  __syncthreads();
  float a = attr[n];
  int c = threadIdx.x;
  if (c < 64) {
    float acc = 0.f;
    #pragma unroll 8
    for (int u = 0; u < 96; ++u) acc += sm[u] * w0[u * 64 + c];
    out[(size_t)n * 320 + c] = CS_ * s[(size_t)n * 160 + c] + CX_ * (acc * a * RS96);
  } else if (c < 160) {
    int t = c - 64, v = t / 3, i = t - v * 3;
    float acc = 0.f;
    #pragma unroll 8
    for (int u = 0; u < 128; ++u) acc += sm[96 + u * 3 + i] * w1[u * 32 + v];
    out[(size_t)n * 320 + c] = CS_ * s[(size_t)n * 160 + c] + CX_ * (acc * a * RS128);
  } else {
    int t = c - 160, v = t / 5, i = t - v * 5;
    float acc = 0.f;
    #pragma unroll 8
    for (int u = 0; u < 96; ++u) acc += sm[480 + u * 5 + i] * w2[u * 32 + v];
    out[(size_t)n * 320 + c] = acc * a * RS96;
  }
}

extern "C" void kernel_launch(void* const* d_in, const int* in_sizes, int n_in,
                              void* d_out, int out_size, void* d_ws, size_t ws_size,
                              hipStream_t stream) {
  const float* node_input = (const float*)d_in[0];
  const float* node_attr  = (const float*)d_in[1];
  const int*   edge_src   = (const int*)d_in[2];
  const int*   edge_dst   = (const int*)d_in[3];
  const float* edge_attr  = (const float*)d_in[4];
  const float* ele        = (const float*)d_in[5];
  const float* sc_w0      = (const float*)d_in[6];
  const float* sc_w1      = (const float*)d_in[7];
  const float* l1_w0      = (const float*)d_in[8];
  const float* l1_w1      = (const float*)d_in[9];
  const float* fc_w0      = (const float*)d_in[10];
  const float* fc_w1      = (const float*)d_in[11];
  const float* l2_w0      = (const float*)d_in[12];
  const float* l2_w1      = (const float*)d_in[13];
  const float* l2_w2      = (const float*)d_in[14];
  float* out = (float*)d_out;

  float* ws  = (float*)d_ws;
  float* y   = ws;                              // N*160
  float* s   = ws + (size_t)N_NODES * 160;      // N*160
  float* agg = ws + (size_t)N_NODES * 320;      // N*960

  // zero agg (ws is poisoned 0xAA before every call)
  hipLaunchKernelGGL(zero_kernel, dim3(N_NODES * 960 / 4 / 256), dim3(256), 0, stream,
                     (float4*)agg, N_NODES * 960 / 4);
  // node linears (s, y)
  hipLaunchKernelGGL(node_pre, dim3(N_NODES * 160 / 256), dim3(256), 0, stream,
                     node_input, node_attr, sc_w0, sc_w1, l1_w0, l1_w1, s, y);
  // fused radial-MLP + tensor-product + scatter
  hipLaunchKernelGGL(edge_kernel, dim3(N_EDGES / 8), dim3(512), 0, stream,
                     y, edge_src, edge_dst, edge_attr, ele, fc_w0, fc_w1, agg);
  // lin2 + self-connection combine
  hipLaunchKernelGGL(node_post, dim3(N_NODES), dim3(320), 0, stream,
                     agg, s, node_attr, l2_w0, l2_w1, l2_w2, out);
}

// Round 2
// 692.600 us; speedup vs baseline: 1.5175x; 1.5175x over previous
//
#include <hip/hip_runtime.h>
#include <cstddef>
#include <cstdint>

#define N_NODES 10000
#define N_EDGES 160000

// ---- constants ----
#define RS8    0.35355339059327373f   // 1/sqrt(8)
#define RS32   0.17677669529663687f   // 1/sqrt(32)
#define RS96   0.10206207261596575f   // 1/sqrt(96)
#define RS128  0.08838834764831845f   // 1/sqrt(128)
#define RS3    0.5773502691896258f    // 1/sqrt(3)
#define SQ3_   1.7320508075688772f
#define SQ5_   2.23606797749979f
#define A_     0.18257418583505536f   // 1/sqrt(30)
#define B_     0.31622776601683794f   // 1/sqrt(10)
#define SILU_C_ 1.6765208f
#define CS_    0.3826834323650898f    // sin(pi/8)
#define CX_    0.9238795325112867f    // cos(pi/8)
#define QDEG   0.25f                  // 1/sqrt(16)

__device__ inline float bf2f(unsigned s) {
  union { unsigned u; float f; } c; c.u = s << 16; return c.f;
}
__device__ inline unsigned short f2bf(float f) {
  union { float f; unsigned u; } c; c.f = f;
  unsigned r = c.u + 0x7fff + ((c.u >> 16) & 1);
  return (unsigned short)(r >> 16);
}

__global__ void k_zero_int(int* __restrict__ p, int n) {
  int i = blockIdx.x * blockDim.x + threadIdx.x;
  if (i < n) p[i] = 0;
}

__global__ void k_hist(const int* __restrict__ edst, int* __restrict__ counts) {
  int e = blockIdx.x * blockDim.x + threadIdx.x;
  if (e < N_EDGES) atomicAdd(&counts[edst[e]], 1);
}

// exclusive scan of 10000 counts -> offs, cur (single block, 256 threads x 40 bins)
__global__ __launch_bounds__(256) void k_scan(const int* __restrict__ counts,
                                              int* __restrict__ offs,
                                              int* __restrict__ cur) {
  __shared__ int ps[256];
  int t = threadIdx.x;
  int base = t * 40;
  int sum = 0;
  for (int i = 0; i < 40; ++i) {
    int idx = base + i;
    if (idx < N_NODES) sum += counts[idx];
  }
  ps[t] = sum;
  __syncthreads();
  for (int off = 1; off < 256; off <<= 1) {
    int v = (t >= off) ? ps[t - off] : 0;
    __syncthreads();
    ps[t] += v;
    __syncthreads();
  }
  int run = (t == 0) ? 0 : ps[t - 1];
  for (int i = 0; i < 40; ++i) {
    int idx = base + i;
    if (idx < N_NODES) {
      int c = counts[idx];
      offs[idx] = run; cur[idx] = run;
      run += c;
    }
  }
}

__global__ void k_scatter(const int* __restrict__ edst, int* __restrict__ cur,
                          int* __restrict__ sorted) {
  int e = blockIdx.x * blockDim.x + threadIdx.x;
  if (e < N_EDGES) {
    int d = edst[e];
    int p = atomicAdd(&cur[d], 1);
    sorted[p] = e;
  }
}

// s[n][0:160], y[n][0:160]: scalar block (64) + vector block (32x3, u-major)
__global__ void node_pre(const float* __restrict__ xin, const float* __restrict__ attr,
                         const float* __restrict__ sc_w0, const float* __restrict__ sc_w1,
                         const float* __restrict__ l1_w0, const float* __restrict__ l1_w1,
                         float* __restrict__ s, float* __restrict__ y) {
  int idx = blockIdx.x * blockDim.x + threadIdx.x;
  int n = idx / 160, c = idx - n * 160;
  const float* xr = xin + (size_t)n * 160;
  float a = attr[n];
  float sv, yv;
  if (c < 64) {
    float s_ = 0.f, y_ = 0.f;
    #pragma unroll 8
    for (int u = 0; u < 64; ++u) {
      float x = xr[u];
      s_ += x * sc_w0[u * 64 + c];
      y_ += x * l1_w0[u * 64 + c];
    }
    sv = s_ * a * 0.125f; yv = y_ * a * 0.125f;
  } else {
    int t = c - 64; int v = t / 3, i = t - v * 3;
    float s_ = 0.f, y_ = 0.f;
    #pragma unroll 8
    for (int u = 0; u < 32; ++u) {
      float x = xr[64 + u * 3 + i];
      s_ += x * sc_w1[u * 32 + v];
      y_ += x * l1_w1[u * 32 + v];
    }
    sv = s_ * a * RS32; yv = y_ * a * RS32;
  }
  s[idx] = sv; y[idx] = yv;
}

// w = (silu(ele@fc0/sqrt8)*SILU_C) @ fc1 / 8, stored bf16.
// 32 edges per 256-thread block; fc1 staged in LDS in 16-row chunks.
__global__ __launch_bounds__(256) void w_gemm(
    const float* __restrict__ ele, const float* __restrict__ fc0,
    const float* __restrict__ fc1, unsigned short* __restrict__ wout) {
  __shared__ __align__(16) float sh_ele[32][9];    // padded
  __shared__ __align__(16) float sh_fc0[512];      // [8][64]
  __shared__ __align__(16) float sh_ht[64 * 32];   // h transposed [k][e]
  __shared__ __align__(16) float sh_fc1[16 * 320];
  int t = threadIdx.x;
  int eb = blockIdx.x * 32;

  { // stage ele (32x8) and fc0 (8x64)
    int e = t >> 3, m = t & 7;
    sh_ele[e][m] = ele[(size_t)(eb + e) * 8 + m];
    sh_fc0[t] = fc0[t];
    sh_fc0[t + 256] = fc0[t + 256];
  }
  __syncthreads();
  { // h: 2048 values, 8 per thread, write transposed [k][e]
    #pragma unroll
    for (int i = 0; i < 8; ++i) {
      int idx = t + i * 256;
      int k = idx >> 5, e = idx & 31;
      float acc = 0.f;
      #pragma unroll
      for (int m = 0; m < 8; ++m) acc += sh_ele[e][m] * sh_fc0[m * 64 + k];
      acc *= RS8;
      sh_ht[k * 32 + e] = SILU_C_ * acc / (1.f + __expf(-acc));
    }
  }

  int wv = t >> 6, lane = t & 63;
  int er = wv * 8;
  float acc[8][5];
  #pragma unroll
  for (int i = 0; i < 8; ++i)
    #pragma unroll
    for (int j = 0; j < 5; ++j) acc[i][j] = 0.f;

  for (int kc = 0; kc < 4; ++kc) {
    __syncthreads();
    { // stage fc1 rows [kc*16, kc*16+16)
      const float4* src = (const float4*)(fc1 + (size_t)kc * 16 * 320);
      float4* dst = (float4*)sh_fc1;
      #pragma unroll
      for (int i = 0; i < 5; ++i) dst[t + i * 256] = src[t + i * 256];
    }
    __syncthreads();
    #pragma unroll
    for (int k = 0; k < 16; ++k) {
      const float* hp = &sh_ht[(kc * 16 + k) * 32 + er];
      float4 a0 = *(const float4*)hp;
      float4 a1 = *(const float4*)(hp + 4);
      float av[8] = {a0.x, a0.y, a0.z, a0.w, a1.x, a1.y, a1.z, a1.w};
      float bv[5];
      #pragma unroll
      for (int j = 0; j < 5; ++j) bv[j] = sh_fc1[k * 320 + lane + 64 * j];
      #pragma unroll
      for (int i = 0; i < 8; ++i)
        #pragma unroll
        for (int j = 0; j < 5; ++j) acc[i][j] += av[i] * bv[j];
    }
  }
  // store bf16
  #pragma unroll
  for (int i = 0; i < 8; ++i) {
    unsigned short* row = wout + (size_t)(eb + er + i) * 320;
    #pragma unroll
    for (int j = 0; j < 5; ++j) row[lane + 64 * j] = f2bf(acc[i][j] * 0.125f);
  }
}

// one wave per node: walk sorted incoming edges, accumulate m[960] in regs,
// then lin2 + self-connection combine -> out[320]. No atomics.
__global__ __launch_bounds__(64) void node_agg(
    const float* __restrict__ y, const float* __restrict__ s,
    const float* __restrict__ attr, const int* __restrict__ esrc,
    const float* __restrict__ eattr, const unsigned short* __restrict__ wbuf,
    const int* __restrict__ sorted, const int* __restrict__ offs,
    const int* __restrict__ counts,
    const float* __restrict__ w0, const float* __restrict__ w1,
    const float* __restrict__ w2, float* __restrict__ out) {
  __shared__ __align__(16) float sh_y[160];
  __shared__ __align__(16) float sh_w[320];
  __shared__ float sh_e[12];
  __shared__ int sh_eid[64];
  __shared__ int sh_src[64];
  __shared__ __align__(16) float sh_m[960];

  int n = blockIdx.x, lane = threadIdx.x;
  int beg = offs[n], cnt = counts[n];
  float acc[15];
  #pragma unroll
  for (int j = 0; j < 15; ++j) acc[j] = 0.f;

  for (int base = 0; base < cnt; base += 64) {
    int nn = min(64, cnt - base);
    __syncthreads();
    if (lane < nn) {
      int e = sorted[beg + base + lane];
      sh_eid[lane] = e;
      sh_src[lane] = esrc[e];
    }
    __syncthreads();
    for (int tt = 0; tt < nn; ++tt) {
      int e = sh_eid[tt];
      int src = sh_src[tt];
      // load y row (160f), w row (320 bf16), SH (9f)
      if (lane < 40) {
        ((float4*)sh_y)[lane] = ((const float4*)(y + (size_t)src * 160))[lane];
        uint4 v = ((const uint4*)(wbuf + (size_t)e * 320))[lane];
        float* dst = &sh_w[lane * 8];
        dst[0] = bf2f(v.x & 0xffffu); dst[1] = bf2f(v.x >> 16);
        dst[2] = bf2f(v.y & 0xffffu); dst[3] = bf2f(v.y >> 16);
        dst[4] = bf2f(v.z & 0xffffu); dst[5] = bf2f(v.z >> 16);
        dst[6] = bf2f(v.w & 0xffffu); dst[7] = bf2f(v.w >> 16);
      }
      if (lane < 9) sh_e[lane] = eattr[(size_t)e * 9 + lane];
      __syncthreads();

      float e0 = sh_e[0];
      float ey = sh_e[1], ez = sh_e[2], ex = sh_e[3];
      float g0 = sh_e[4], g1 = sh_e[5], g2 = sh_e[6], g3 = sh_e[7], g4 = sh_e[8];
      const float* Y0 = sh_y;
      const float* X1 = sh_y + 64;
      const float* W  = sh_w;

      #pragma unroll
      for (int j = 0; j < 15; ++j) {
        int c = lane + 64 * j;
        float val;
        if (c < 64) {
          val = Y0[c] * e0 * W[c];
        } else if (c < 96) {
          int u = c - 64;
          val = RS3 * (X1[u*3] * ey + X1[u*3+1] * ez + X1[u*3+2] * ex) * W[224 + u];
        } else if (c < 288) {
          int t2 = c - 96, u = t2 / 3, k = t2 - u * 3;
          float ek = (k == 0) ? ey : ((k == 1) ? ez : ex);
          val = Y0[u] * ek * W[64 + u];
        } else if (c < 384) {
          int t2 = c - 288, u = t2 / 3, k = t2 - u * 3;
          val = X1[u*3 + k] * e0 * W[192 + u];
        } else if (c < 480) {
          int t2 = c - 384, u = t2 / 3, k = t2 - u * 3;
          float xy = X1[u*3], xz = X1[u*3+1], xx = X1[u*3+2];
          float K;
          if (k == 0)      K = B_ * (xx * g0 + xz * g1 - xy * g4) - A_ * xy * g2;
          else if (k == 1) K = B_ * (xy * g1 + xx * g3) + 2.f * A_ * xz * g2;
          else             K = B_ * (xy * g0 + xz * g3 + xx * g4) - A_ * xx * g2;
          val = SQ3_ * W[288 + u] * K;
        } else if (c < 800) {
          int t2 = c - 480, u = t2 / 5, k = t2 - u * 5;
          float gk = (k == 0) ? g0 : ((k == 1) ? g1 : ((k == 2) ? g2 : ((k == 3) ? g3 : g4)));
          val = Y0[u] * gk * W[128 + u];
        } else {
          int t2 = c - 800, u = t2 / 5, k = t2 - u * 5;
          float xy = X1[u*3], xz = X1[u*3+1], xx = X1[u*3+2];
          float K;
          if (k == 0)      K = -B_ * (xy * ex + xx * ey);
          else if (k == 1) K = -B_ * (xy * ez + xz * ey);
          else if (k == 2) K =  A_ * (xy * ey + xx * ex - 2.f * xz * ez);
          else if (k == 3) K = -B_ * (xz * ex + xx * ez);
          else             K =  B_ * (xy * ey - xx * ex);
          val = SQ5_ * W[256 + u] * K;
        }
        acc[j] += val;
      }
      __syncthreads();
    }
  }

  // write m to LDS
  __syncthreads();
  #pragma unroll
  for (int j = 0; j < 15; ++j) sh_m[lane + 64 * j] = acc[j] * QDEG;
  __syncthreads();

  // lin2 + combine: 5 output cols per lane
  float a = attr[n];
  const float* srow = s + (size_t)n * 160;
  float* orow = out + (size_t)n * 320;
  #pragma unroll
  for (int jo = 0; jo < 5; ++jo) {
    int oc = lane + 64 * jo;
    float res;
    if (oc < 64) {
      float o = 0.f;
      #pragma unroll 8
      for (int u = 0; u < 96; ++u) o += sh_m[u] * w0[u * 64 + oc];
      res = CS_ * srow[oc] + CX_ * (o * a * RS96);
    } else if (oc < 160) {
      int t2 = oc - 64, v = t2 / 3, i = t2 - v * 3;
      float o = 0.f;
      #pragma unroll 8
      for (int u = 0; u < 128; ++u) o += sh_m[96 + u * 3 + i] * w1[u * 32 + v];
      res = CS_ * srow[oc] + CX_ * (o * a * RS128);
    } else {
      int t2 = oc - 160, v = t2 / 5, k = t2 - v * 5;
      float o = 0.f;
      #pragma unroll 8
      for (int u = 0; u < 96; ++u) o += sh_m[480 + u * 5 + k] * w2[u * 32 + v];
      res = o * a * RS96;
    }
    orow[oc] = res;
  }
}

extern "C" void kernel_launch(void* const* d_in, const int* in_sizes, int n_in,
                              void* d_out, int out_size, void* d_ws, size_t ws_size,
                              hipStream_t stream) {
  const float* node_input = (const float*)d_in[0];
  const float* node_attr  = (const float*)d_in[1];
  const int*   edge_src   = (const int*)d_in[2];
  const int*   edge_dst   = (const int*)d_in[3];
  const float* edge_attr  = (const float*)d_in[4];
  const float* ele        = (const float*)d_in[5];
  const float* sc_w0      = (const float*)d_in[6];
  const float* sc_w1      = (const float*)d_in[7];
  const float* l1_w0      = (const float*)d_in[8];
  const float* l1_w1      = (const float*)d_in[9];
  const float* fc_w0      = (const float*)d_in[10];
  const float* fc_w1      = (const float*)d_in[11];
  const float* l2_w0      = (const float*)d_in[12];
  const float* l2_w1      = (const float*)d_in[13];
  const float* l2_w2      = (const float*)d_in[14];
  float* out = (float*)d_out;

  float* ws = (float*)d_ws;
  float* y = ws;                                        // 1.6M f
  float* s = y + (size_t)N_NODES * 160;                 // 1.6M f
  unsigned short* wbuf = (unsigned short*)(s + (size_t)N_NODES * 160);  // 51.2M u16
  int* counts = (int*)(wbuf + (size_t)N_EDGES * 320);
  int* offs   = counts + 10240;
  int* cur    = offs + 10240;
  int* sorted = cur + 10240;                            // 160000 int

  // sort edges by dst
  hipLaunchKernelGGL(k_zero_int, dim3(40), dim3(256), 0, stream, counts, N_NODES);
  hipLaunchKernelGGL(k_hist, dim3((N_EDGES + 255) / 256), dim3(256), 0, stream,
                     edge_dst, counts);
  hipLaunchKernelGGL(k_scan, dim3(1), dim3(256), 0, stream, counts, offs, cur);
  hipLaunchKernelGGL(k_scatter, dim3((N_EDGES + 255) / 256), dim3(256), 0, stream,
                     edge_dst, cur, sorted);
  // node linears (s, y)
  hipLaunchKernelGGL(node_pre, dim3(N_NODES * 160 / 256), dim3(256), 0, stream,
                     node_input, node_attr, sc_w0, sc_w1, l1_w0, l1_w1, s, y);
  // radial MLP -> w (bf16)
  hipLaunchKernelGGL(w_gemm, dim3(N_EDGES / 32), dim3(256), 0, stream,
                     ele, fc_w0, fc_w1, wbuf);
  // gather-aggregate + lin2 + combine
  hipLaunchKernelGGL(node_agg, dim3(N_NODES), dim3(64), 0, stream,
                     y, s, node_attr, edge_src, edge_attr, wbuf,
                     sorted, offs, counts, l2_w0, l2_w1, l2_w2, out);
}

// Round 3
// 572.441 us; speedup vs baseline: 1.8361x; 1.2099x over previous
//
#include <hip/hip_runtime.h>
#include <cstddef>
#include <cstdint>

#define N_NODES 10000
#define N_EDGES 160000

// ---- constants ----
#define RS8    0.35355339059327373f   // 1/sqrt(8)
#define RS32   0.17677669529663687f   // 1/sqrt(32)
#define RS96   0.10206207261596575f   // 1/sqrt(96)
#define RS128  0.08838834764831845f   // 1/sqrt(128)
#define RS3    0.5773502691896258f    // 1/sqrt(3)
#define SQ3_   1.7320508075688772f
#define SQ5_   2.23606797749979f
#define A_     0.18257418583505536f   // 1/sqrt(30)
#define B_     0.31622776601683794f   // 1/sqrt(10)
#define SILU_C_ 1.6765208f
#define CS_    0.3826834323650898f    // sin(pi/8)
#define CX_    0.9238795325112867f    // cos(pi/8)
#define QDEG   0.25f                  // 1/sqrt(16)

__device__ inline float bf2f(unsigned s) {
  union { unsigned u; float f; } c; c.u = s << 16; return c.f;
}
__device__ inline unsigned short f2bf(float f) {
  union { float f; unsigned u; } c; c.f = f;
  unsigned r = c.u + 0x7fff + ((c.u >> 16) & 1);
  return (unsigned short)(r >> 16);
}
// w split layout: entries 8q..8q+3 at [q*4..], 8q+4..8q+7 at [160+q*4..]
__device__ inline int widx(int i) {
  return ((i & 4) ? 160 : 0) + ((i >> 3) << 2) + (i & 3);
}

__global__ void k_zero_int(int* __restrict__ p, int n) {
  int i = blockIdx.x * blockDim.x + threadIdx.x;
  if (i < n) p[i] = 0;
}

__global__ void k_hist(const int* __restrict__ edst, int* __restrict__ counts) {
  int e = blockIdx.x * blockDim.x + threadIdx.x;
  if (e < N_EDGES) atomicAdd(&counts[edst[e]], 1);
}

__global__ __launch_bounds__(256) void k_scan(const int* __restrict__ counts,
                                              int* __restrict__ offs,
                                              int* __restrict__ cur) {
  __shared__ int ps[256];
  int t = threadIdx.x;
  int base = t * 40;
  int sum = 0;
  for (int i = 0; i < 40; ++i) {
    int idx = base + i;
    if (idx < N_NODES) sum += counts[idx];
  }
  ps[t] = sum;
  __syncthreads();
  for (int off = 1; off < 256; off <<= 1) {
    int v = (t >= off) ? ps[t - off] : 0;
    __syncthreads();
    ps[t] += v;
    __syncthreads();
  }
  int run = (t == 0) ? 0 : ps[t - 1];
  for (int i = 0; i < 40; ++i) {
    int idx = base + i;
    if (idx < N_NODES) {
      int c = counts[idx];
      offs[idx] = run; cur[idx] = run;
      run += c;
    }
  }
}

__global__ void k_scatter(const int* __restrict__ edst, int* __restrict__ cur,
                          int* __restrict__ sorted) {
  int e = blockIdx.x * blockDim.x + threadIdx.x;
  if (e < N_EDGES) {
    int d = edst[e];
    int p = atomicAdd(&cur[d], 1);
    sorted[p] = e;
  }
}

// s[n][0:160], y[n][0:160]: scalar block (64) + vector block (32x3, u-major)
__global__ void node_pre(const float* __restrict__ xin, const float* __restrict__ attr,
                         const float* __restrict__ sc_w0, const float* __restrict__ sc_w1,
                         const float* __restrict__ l1_w0, const float* __restrict__ l1_w1,
                         float* __restrict__ s, float* __restrict__ y) {
  int idx = blockIdx.x * blockDim.x + threadIdx.x;
  int n = idx / 160, c = idx - n * 160;
  const float* xr = xin + (size_t)n * 160;
  float a = attr[n];
  float sv, yv;
  if (c < 64) {
    float s_ = 0.f, y_ = 0.f;
    #pragma unroll 8
    for (int u = 0; u < 64; ++u) {
      float x = xr[u];
      s_ += x * sc_w0[u * 64 + c];
      y_ += x * l1_w0[u * 64 + c];
    }
    sv = s_ * a * 0.125f; yv = y_ * a * 0.125f;
  } else {
    int t = c - 64; int v = t / 3, i = t - v * 3;
    float s_ = 0.f, y_ = 0.f;
    #pragma unroll 8
    for (int u = 0; u < 32; ++u) {
      float x = xr[64 + u * 3 + i];
      s_ += x * sc_w1[u * 32 + v];
      y_ += x * l1_w1[u * 32 + v];
    }
    sv = s_ * a * RS32; yv = y_ * a * RS32;
  }
  s[idx] = sv; y[idx] = yv;
}

// w = (silu(ele@fc0/sqrt8)*SILU_C) @ fc1 / 8, stored bf16.
__global__ __launch_bounds__(256) void w_gemm(
    const float* __restrict__ ele, const float* __restrict__ fc0,
    const float* __restrict__ fc1, unsigned short* __restrict__ wout) {
  __shared__ __align__(16) float sh_ele[32][9];
  __shared__ __align__(16) float sh_fc0[512];
  __shared__ __align__(16) float sh_ht[64 * 32];
  __shared__ __align__(16) float sh_fc1[16 * 320];
  int t = threadIdx.x;
  int eb = blockIdx.x * 32;

  {
    int e = t >> 3, m = t & 7;
    sh_ele[e][m] = ele[(size_t)(eb + e) * 8 + m];
    sh_fc0[t] = fc0[t];
    sh_fc0[t + 256] = fc0[t + 256];
  }
  __syncthreads();
  {
    #pragma unroll
    for (int i = 0; i < 8; ++i) {
      int idx = t + i * 256;
      int k = idx >> 5, e = idx & 31;
      float acc = 0.f;
      #pragma unroll
      for (int m = 0; m < 8; ++m) acc += sh_ele[e][m] * sh_fc0[m * 64 + k];
      acc *= RS8;
      sh_ht[k * 32 + e] = SILU_C_ * acc / (1.f + __expf(-acc));
    }
  }

  int wv = t >> 6, lane = t & 63;
  int er = wv * 8;
  float acc[8][5];
  #pragma unroll
  for (int i = 0; i < 8; ++i)
    #pragma unroll
    for (int j = 0; j < 5; ++j) acc[i][j] = 0.f;

  for (int kc = 0; kc < 4; ++kc) {
    __syncthreads();
    {
      const float4* src = (const float4*)(fc1 + (size_t)kc * 16 * 320);
      float4* dst = (float4*)sh_fc1;
      #pragma unroll
      for (int i = 0; i < 5; ++i) dst[t + i * 256] = src[t + i * 256];
    }
    __syncthreads();
    #pragma unroll
    for (int k = 0; k < 16; ++k) {
      const float* hp = &sh_ht[(kc * 16 + k) * 32 + er];
      float4 a0 = *(const float4*)hp;
      float4 a1 = *(const float4*)(hp + 4);
      float av[8] = {a0.x, a0.y, a0.z, a0.w, a1.x, a1.y, a1.z, a1.w};
      float bv[5];
      #pragma unroll
      for (int j = 0; j < 5; ++j) bv[j] = sh_fc1[k * 320 + lane + 64 * j];
      #pragma unroll
      for (int i = 0; i < 8; ++i)
        #pragma unroll
        for (int j = 0; j < 5; ++j) acc[i][j] += av[i] * bv[j];
    }
  }
  #pragma unroll
  for (int i = 0; i < 8; ++i) {
    unsigned short* row = wout + (size_t)(eb + er + i) * 320;
    #pragma unroll
    for (int j = 0; j < 5; ++j) row[lane + 64 * j] = f2bf(acc[i][j] * 0.125f);
  }
}

__device__ inline float lin2_col(const float* __restrict__ sm,
                                 const float* __restrict__ w0,
                                 const float* __restrict__ w1,
                                 const float* __restrict__ w2,
                                 const float* __restrict__ srow,
                                 float a, int oc) {
  if (oc < 64) {
    float o = 0.f;
    #pragma unroll 8
    for (int u = 0; u < 96; ++u) o += sm[u] * w0[u * 64 + oc];
    return CS_ * srow[oc] + CX_ * (o * a * RS96);
  } else if (oc < 160) {
    int t = oc - 64, v = t / 3, i = t - v * 3;
    float o = 0.f;
    #pragma unroll 8
    for (int u = 0; u < 128; ++u) o += sm[96 + u * 3 + i] * w1[u * 32 + v];
    return CS_ * srow[oc] + CX_ * (o * a * RS128);
  } else {
    int t = oc - 160, v = t / 5, k = t - v * 5;
    float o = 0.f;
    #pragma unroll 8
    for (int u = 0; u < 96; ++u) o += sm[480 + u * 5 + k] * w2[u * 32 + v];
    return o * a * RS96;
  }
}

// 4 waves per node, one edge per wave, 2-deep register prefetch pipeline.
__global__ __launch_bounds__(256) void node_agg(
    const float* __restrict__ y, const float* __restrict__ s,
    const float* __restrict__ attr, const int* __restrict__ esrc,
    const float* __restrict__ eattr, const unsigned short* __restrict__ wbuf,
    const int* __restrict__ sorted, const int* __restrict__ offs,
    const int* __restrict__ counts,
    const float* __restrict__ w0, const float* __restrict__ w1,
    const float* __restrict__ w2, float* __restrict__ out) {
  __shared__ __align__(16) float sh_y[4][2][160];
  __shared__ __align__(16) float sh_w[4][2][320];
  __shared__ __align__(16) float sh_e[4][2][16];
  __shared__ int sh_eid[256];
  __shared__ int sh_src[256];
  __shared__ __align__(16) float sh_part[4][960];

  int n = blockIdx.x;
  int tid = threadIdx.x;
  int wid = tid >> 6, lane = tid & 63;
  int beg = offs[n], cnt = counts[n];

  float acc[15];
  #pragma unroll
  for (int j = 0; j < 15; ++j) acc[j] = 0.f;

  for (int base = 0; base < cnt; base += 256) {
    int nn = min(256, cnt - base);
    __syncthreads();
    for (int l = tid; l < nn; l += 256) sh_eid[l] = sorted[beg + base + l];
    __syncthreads();
    for (int l = tid; l < nn; l += 256) sh_src[l] = esrc[sh_eid[l]];
    __syncthreads();

    int T = (nn + 3) >> 2;
    float4 py; uint4 pw; float pe;
    {  // preamble prefetch: edge local index = wid
      int l = wid;
      if (l < nn) {
        int e = sh_eid[l], src = sh_src[l];
        if (lane < 40) py = ((const float4*)(y + (size_t)src * 160))[lane];
        if (lane >= 24) pw = ((const uint4*)(wbuf + (size_t)e * 320))[lane - 24];
        if (lane < 9)  pe = eattr[(size_t)e * 9 + lane];
      }
    }
    for (int it = 0; it < T; ++it) {
      int lc = wid + it * 4;
      bool vc = lc < nn;
      int b = it & 1;
      float* Yb = sh_y[wid][b];
      float* Wb = sh_w[wid][b];
      float* Eb = sh_e[wid][b];
      if (vc) {  // stage current edge regs -> wave-private LDS
        if (lane < 40) ((float4*)Yb)[lane] = py;
        if (lane >= 24) {
          int q = lane - 24;
          float4 lo, hi;
          lo.x = bf2f(pw.x & 0xffffu); lo.y = bf2f(pw.x >> 16);
          lo.z = bf2f(pw.y & 0xffffu); lo.w = bf2f(pw.y >> 16);
          hi.x = bf2f(pw.z & 0xffffu); hi.y = bf2f(pw.z >> 16);
          hi.z = bf2f(pw.w & 0xffffu); hi.w = bf2f(pw.w >> 16);
          ((float4*)Wb)[q] = lo;
          ((float4*)(Wb + 160))[q] = hi;
        }
        if (lane < 9) Eb[lane] = pe;
      }
      __syncthreads();
      {  // prefetch next edge for this wave
        int ln = lc + 4;
        if (ln < nn) {
          int e = sh_eid[ln], src = sh_src[ln];
          if (lane < 40) py = ((const float4*)(y + (size_t)src * 160))[lane];
          if (lane >= 24) pw = ((const uint4*)(wbuf + (size_t)e * 320))[lane - 24];
          if (lane < 9)  pe = eattr[(size_t)e * 9 + lane];
        }
      }
      if (vc) {  // compute current edge
        float e0 = Eb[0];
        float ey = Eb[1], ez = Eb[2], ex = Eb[3];
        float g0 = Eb[4], g1 = Eb[5], g2 = Eb[6], g3 = Eb[7], g4 = Eb[8];
        const float* Y0 = Yb;
        const float* X1 = Yb + 64;

        #pragma unroll
        for (int j = 0; j < 15; ++j) {
          int c = lane + 64 * j;
          float val;
          if (c < 64) {
            val = Y0[c] * e0 * Wb[widx(c)];
          } else if (c < 96) {
            int u = c - 64;
            val = RS3 * (X1[u*3] * ey + X1[u*3+1] * ez + X1[u*3+2] * ex) * Wb[widx(224 + u)];
          } else if (c < 288) {
            int t2 = c - 96, u = t2 / 3, k = t2 - u * 3;
            float ek = (k == 0) ? ey : ((k == 1) ? ez : ex);
            val = Y0[u] * ek * Wb[widx(64 + u)];
          } else if (c < 384) {
            int t2 = c - 288, u = t2 / 3, k = t2 - u * 3;
            val = X1[u*3 + k] * e0 * Wb[widx(192 + u)];
          } else if (c < 480) {
            int t2 = c - 384, u = t2 / 3, k = t2 - u * 3;
            float xy = X1[u*3], xz = X1[u*3+1], xx = X1[u*3+2];
            float K;
            if (k == 0)      K = B_ * (xx * g0 + xz * g1 - xy * g4) - A_ * xy * g2;
            else if (k == 1) K = B_ * (xy * g1 + xx * g3) + 2.f * A_ * xz * g2;
            else             K = B_ * (xy * g0 + xz * g3 + xx * g4) - A_ * xx * g2;
            val = SQ3_ * Wb[widx(288 + u)] * K;
          } else if (c < 800) {
            int t2 = c - 480, u = t2 / 5, k = t2 - u * 5;
            float gk = (k == 0) ? g0 : ((k == 1) ? g1 : ((k == 2) ? g2 : ((k == 3) ? g3 : g4)));
            val = Y0[u] * gk * Wb[widx(128 + u)];
          } else {
            int t2 = c - 800, u = t2 / 5, k = t2 - u * 5;
            float xy = X1[u*3], xz = X1[u*3+1], xx = X1[u*3+2];
            float K;
            if (k == 0)      K = -B_ * (xy * ex + xx * ey);
            else if (k == 1) K = -B_ * (xy * ez + xz * ey);
            else if (k == 2) K =  A_ * (xy * ey + xx * ex - 2.f * xz * ez);
            else if (k == 3) K = -B_ * (xz * ex + xx * ez);
            else             K =  B_ * (xy * ey - xx * ex);
            val = SQ5_ * Wb[widx(256 + u)] * K;
          }
          acc[j] += val;
        }
      }
    }
  }

  // cross-wave reduce
  __syncthreads();
  #pragma unroll
  for (int j = 0; j < 15; ++j) sh_part[wid][lane + 64 * j] = acc[j];
  __syncthreads();
  for (int i = tid; i < 960; i += 256)
    sh_part[0][i] = ((sh_part[0][i] + sh_part[1][i]) +
                     (sh_part[2][i] + sh_part[3][i])) * QDEG;
  __syncthreads();

  // lin2 + combine
  float a = attr[n];
  const float* srow = s + (size_t)n * 160;
  float* orow = out + (size_t)n * 320;
  const float* sm = sh_part[0];
  orow[tid] = lin2_col(sm, w0, w1, w2, srow, a, tid);
  if (tid < 64) orow[256 + tid] = lin2_col(sm, w0, w1, w2, srow, a, 256 + tid);
}

extern "C" void kernel_launch(void* const* d_in, const int* in_sizes, int n_in,
                              void* d_out, int out_size, void* d_ws, size_t ws_size,
                              hipStream_t stream) {
  const float* node_input = (const float*)d_in[0];
  const float* node_attr  = (const float*)d_in[1];
  const int*   edge_src   = (const int*)d_in[2];
  const int*   edge_dst   = (const int*)d_in[3];
  const float* edge_attr  = (const float*)d_in[4];
  const float* ele        = (const float*)d_in[5];
  const float* sc_w0      = (const float*)d_in[6];
  const float* sc_w1      = (const float*)d_in[7];
  const float* l1_w0      = (const float*)d_in[8];
  const float* l1_w1      = (const float*)d_in[9];
  const float* fc_w0      = (const float*)d_in[10];
  const float* fc_w1      = (const float*)d_in[11];
  const float* l2_w0      = (const float*)d_in[12];
  const float* l2_w1      = (const float*)d_in[13];
  const float* l2_w2      = (const float*)d_in[14];
  float* out = (float*)d_out;

  float* ws = (float*)d_ws;
  float* y = ws;                                        // N*160 f
  float* s = y + (size_t)N_NODES * 160;                 // N*160 f
  unsigned short* wbuf = (unsigned short*)(s + (size_t)N_NODES * 160);  // E*320 u16
  int* counts = (int*)(wbuf + (size_t)N_EDGES * 320);
  int* offs   = counts + 10240;
  int* cur    = offs + 10240;
  int* sorted = cur + 10240;                            // E int

  hipLaunchKernelGGL(k_zero_int, dim3(40), dim3(256), 0, stream, counts, N_NODES);
  hipLaunchKernelGGL(k_hist, dim3((N_EDGES + 255) / 256), dim3(256), 0, stream,
                     edge_dst, counts);
  hipLaunchKernelGGL(k_scan, dim3(1), dim3(256), 0, stream, counts, offs, cur);
  hipLaunchKernelGGL(k_scatter, dim3((N_EDGES + 255) / 256), dim3(256), 0, stream,
                     edge_dst, cur, sorted);
  hipLaunchKernelGGL(node_pre, dim3(N_NODES * 160 / 256), dim3(256), 0, stream,
                     node_input, node_attr, sc_w0, sc_w1, l1_w0, l1_w1, s, y);
  hipLaunchKernelGGL(w_gemm, dim3(N_EDGES / 32), dim3(256), 0, stream,
                     ele, fc_w0, fc_w1, wbuf);
  hipLaunchKernelGGL(node_agg, dim3(N_NODES), dim3(256), 0, stream,
                     y, s, node_attr, edge_src, edge_attr, wbuf,
                     sorted, offs, counts, l2_w0, l2_w1, l2_w2, out);
}

// Round 5
// 483.258 us; speedup vs baseline: 2.1749x; 1.1845x over previous
//
#include <hip/hip_runtime.h>
#include <cstddef>
#include <cstdint>

#define N_NODES 10000
#define N_EDGES 160000

// ---- constants ----
#define RS8    0.35355339059327373f   // 1/sqrt(8)
#define RS32   0.17677669529663687f   // 1/sqrt(32)
#define RS96   0.10206207261596575f   // 1/sqrt(96)
#define RS128  0.08838834764831845f   // 1/sqrt(128)
#define RS3    0.5773502691896258f    // 1/sqrt(3)
#define SQ3_   1.7320508075688772f
#define SQ5_   2.23606797749979f
#define A_     0.18257418583505536f   // 1/sqrt(30)
#define B_     0.31622776601683794f   // 1/sqrt(10)
#define SILU_C_ 1.6765208f
#define CS_    0.3826834323650898f    // sin(pi/8)
#define CX_    0.9238795325112867f    // cos(pi/8)
#define QDEG   0.25f                  // 1/sqrt(16)

typedef __attribute__((ext_vector_type(8))) short bf16x8;
typedef __attribute__((ext_vector_type(4))) float f32x4;

__device__ inline float bf2f(unsigned v) {
  union { unsigned u; float f; } c; c.u = v << 16; return c.f;
}
__device__ inline unsigned short f2bf(float f) {
  union { float f; unsigned u; } c; c.f = f;
  unsigned r = c.u + 0x7fff + ((c.u >> 16) & 1);
  return (unsigned short)(r >> 16);
}

__global__ void k_zero_int(int* __restrict__ p, int n) {
  int i = blockIdx.x * blockDim.x + threadIdx.x;
  if (i < n) p[i] = 0;
}

__global__ void k_hist(const int* __restrict__ edst, int* __restrict__ counts) {
  int e = blockIdx.x * blockDim.x + threadIdx.x;
  if (e < N_EDGES) atomicAdd(&counts[edst[e]], 1);
}

__global__ __launch_bounds__(256) void k_scan(const int* __restrict__ counts,
                                              int* __restrict__ offs,
                                              int* __restrict__ cur) {
  __shared__ int ps[256];
  int t = threadIdx.x;
  int base = t * 40;
  int sum = 0;
  for (int i = 0; i < 40; ++i) {
    int idx = base + i;
    if (idx < N_NODES) sum += counts[idx];
  }
  ps[t] = sum;
  __syncthreads();
  for (int off = 1; off < 256; off <<= 1) {
    int v = (t >= off) ? ps[t - off] : 0;
    __syncthreads();
    ps[t] += v;
    __syncthreads();
  }
  int run = (t == 0) ? 0 : ps[t - 1];
  for (int i = 0; i < 40; ++i) {
    int idx = base + i;
    if (idx < N_NODES) {
      int c = counts[idx];
      offs[idx] = run; cur[idx] = run;
      run += c;
    }
  }
}

__global__ void k_scatter(const int* __restrict__ edst, int* __restrict__ cur,
                          int* __restrict__ sorted) {
  int e = blockIdx.x * blockDim.x + threadIdx.x;
  if (e < N_EDGES) {
    int d = edst[e];
    int p = atomicAdd(&cur[d], 1);
    sorted[p] = e;
  }
}

// fc1 (64x320 f32) -> bf16 packed in MFMA B-fragment order:
// fc1p[(((t*2+kq)*16 + n)*4 + q)*8 + j] = fc1[(kq*32+q*8+j)*320 + t*16+n]
__global__ void fc1p_build(const float* __restrict__ fc1,
                           unsigned short* __restrict__ fc1p) {
  int i = blockIdx.x * blockDim.x + threadIdx.x;
  if (i >= 20480) return;
  int j = i & 7, q = (i >> 3) & 3, n = (i >> 5) & 15, kq = (i >> 9) & 1, t = i >> 10;
  int k = kq * 32 + q * 8 + j;
  fc1p[i] = f2bf(fc1[k * 320 + t * 16 + n]);
}

// s[n][0:160], y[n][0:160]
__global__ void node_pre(const float* __restrict__ xin, const float* __restrict__ attr,
                         const float* __restrict__ sc_w0, const float* __restrict__ sc_w1,
                         const float* __restrict__ l1_w0, const float* __restrict__ l1_w1,
                         float* __restrict__ s, float* __restrict__ y) {
  int idx = blockIdx.x * blockDim.x + threadIdx.x;
  int n = idx / 160, c = idx - n * 160;
  const float* xr = xin + (size_t)n * 160;
  float a = attr[n];
  float sv, yv;
  if (c < 64) {
    float s_ = 0.f, y_ = 0.f;
    #pragma unroll 8
    for (int u = 0; u < 64; ++u) {
      float x = xr[u];
      s_ += x * sc_w0[u * 64 + c];
      y_ += x * l1_w0[u * 64 + c];
    }
    sv = s_ * a * 0.125f; yv = y_ * a * 0.125f;
  } else {
    int t = c - 64; int v = t / 3, i = t - v * 3;
    float s_ = 0.f, y_ = 0.f;
    #pragma unroll 8
    for (int u = 0; u < 32; ++u) {
      float x = xr[64 + u * 3 + i];
      s_ += x * sc_w1[u * 32 + v];
      y_ += x * l1_w1[u * 32 + v];
    }
    sv = s_ * a * RS32; yv = y_ * a * RS32;
  }
  s[idx] = sv; y[idx] = yv;
}

// MFMA bf16 radial GEMM over 64 SORTED edges per block; writes w rows at the
// sorted position (sequential for node_agg) + permuted eattr/src streams.
__global__ __launch_bounds__(256) void w_gemm(
    const float* __restrict__ ele, const float* __restrict__ fc0,
    const int* __restrict__ sorted, const int* __restrict__ esrc,
    const float* __restrict__ eattr, const unsigned short* __restrict__ fc1p,
    unsigned short* __restrict__ wout, float* __restrict__ ed_s,
    int* __restrict__ src_s) {
  __shared__ int sh_ids[64];
  __shared__ __align__(16) float sh_ele[64][8];
  __shared__ __align__(16) unsigned short sh_h[64 * 72];  // 72-stride pad
  int t = threadIdx.x;
  int eb = blockIdx.x * 64;

  if (t < 64) {
    int id = sorted[eb + t];
    sh_ids[t] = id;
    src_s[eb + t] = esrc[id];
  }
  __syncthreads();
  if (t < 128) {
    int e = t >> 1, hh = t & 1;
    ((float4*)&sh_ele[e][0])[hh] = ((const float4*)(ele + (size_t)sh_ids[e] * 8))[hh];
  }
  for (int i = t; i < 576; i += 256) {
    int e = i / 9, k = i - e * 9;
    ed_s[(size_t)(eb + e) * 12 + k] = eattr[(size_t)sh_ids[e] * 9 + k];
  }
  __syncthreads();
  // h = silu(ele@fc0/sqrt8)*SILU_C -> bf16, A-layout [edge][k], stride 72
  #pragma unroll
  for (int ii = 0; ii < 16; ++ii) {
    int idx = t + ii * 256;
    int e = idx >> 6, k = idx & 63;
    float acc = 0.f;
    #pragma unroll
    for (int m = 0; m < 8; ++m) acc += sh_ele[e][m] * fc0[m * 64 + k];
    acc *= RS8;
    float hv = SILU_C_ * acc / (1.f + __expf(-acc));
    sh_h[e * 72 + k] = f2bf(hv);
  }
  __syncthreads();

  int wv = t >> 6, lane = t & 63;
  int m0 = wv * 16;
  int mrow = lane & 15, quad = lane >> 4;
  const bf16x8* A0 = (const bf16x8*)(sh_h + (m0 + mrow) * 72 + quad * 8);
  const bf16x8* A1 = (const bf16x8*)(sh_h + (m0 + mrow) * 72 + 32 + quad * 8);
  bf16x8 a0 = *A0, a1 = *A1;
  #pragma unroll 4
  for (int t20 = 0; t20 < 20; ++t20) {
    f32x4 acc = {0.f, 0.f, 0.f, 0.f};
    bf16x8 b0 = *(const bf16x8*)(fc1p + ((size_t)((t20 * 2 + 0) * 16 + mrow) * 4 + quad) * 8);
    bf16x8 b1 = *(const bf16x8*)(fc1p + ((size_t)((t20 * 2 + 1) * 16 + mrow) * 4 + quad) * 8);
    acc = __builtin_amdgcn_mfma_f32_16x16x32_bf16(a0, b0, acc, 0, 0, 0);
    acc = __builtin_amdgcn_mfma_f32_16x16x32_bf16(a1, b1, acc, 0, 0, 0);
    #pragma unroll
    for (int r = 0; r < 4; ++r) {
      int row = m0 + quad * 4 + r;
      wout[(size_t)(eb + row) * 320 + t20 * 16 + mrow] = f2bf(acc[r] * 0.125f);
    }
  }
}

__device__ inline float lin2_col(const float* __restrict__ sm,
                                 const float* __restrict__ w0,
                                 const float* __restrict__ w1,
                                 const float* __restrict__ w2,
                                 const float* __restrict__ srow,
                                 float a, int oc) {
  if (oc < 64) {
    float o = 0.f;
    #pragma unroll 8
    for (int u = 0; u < 96; ++u) o += sm[u] * w0[u * 64 + oc];
    return CS_ * srow[oc] + CX_ * (o * a * RS96);
  } else if (oc < 160) {
    int t = oc - 64, v = t / 3, i = t - v * 3;
    float o = 0.f;
    #pragma unroll 8
    for (int u = 0; u < 128; ++u) o += sm[96 + u * 3 + i] * w1[u * 32 + v];
    return CS_ * srow[oc] + CX_ * (o * a * RS128);
  } else {
    int t = oc - 160, v = t / 5, k = t - v * 5;
    float o = 0.f;
    #pragma unroll 8
    for (int u = 0; u < 96; ++u) o += sm[480 + u * 5 + k] * w2[u * 32 + v];
    return o * a * RS96;
  }
}

__device__ inline void edge_compute(const float* __restrict__ Yb,
                                    const unsigned short* __restrict__ Wp,
                                    const float* __restrict__ Eb,
                                    int lane, float* __restrict__ acc) {
  float e0 = Eb[0];
  float ey = Eb[1], ez = Eb[2], ex = Eb[3];
  float g0 = Eb[4], g1 = Eb[5], g2 = Eb[6], g3 = Eb[7], g4 = Eb[8];
  const float* Y0 = Yb;
  const float* X1 = Yb + 64;
  #pragma unroll
  for (int j = 0; j < 15; ++j) {
    int c = lane + 64 * j;
    float val;
    if (c < 64) {
      val = Y0[c] * e0 * bf2f(Wp[c]);
    } else if (c < 96) {
      int u = c - 64;
      val = RS3 * (X1[u*3] * ey + X1[u*3+1] * ez + X1[u*3+2] * ex) * bf2f(Wp[224 + u]);
    } else if (c < 288) {
      int t2 = c - 96, u = t2 / 3, k = t2 - u * 3;
      float ek = (k == 0) ? ey : ((k == 1) ? ez : ex);
      val = Y0[u] * ek * bf2f(Wp[64 + u]);
    } else if (c < 384) {
      int t2 = c - 288, u = t2 / 3, k = t2 - u * 3;
      val = X1[u*3 + k] * e0 * bf2f(Wp[192 + u]);
    } else if (c < 480) {
      int t2 = c - 384, u = t2 / 3, k = t2 - u * 3;
      float xy = X1[u*3], xz = X1[u*3+1], xx = X1[u*3+2];
      float K;
      if (k == 0)      K = B_ * (xx * g0 + xz * g1 - xy * g4) - A_ * xy * g2;
      else if (k == 1) K = B_ * (xy * g1 + xx * g3) + 2.f * A_ * xz * g2;
      else             K = B_ * (xy * g0 + xz * g3 + xx * g4) - A_ * xx * g2;
      val = SQ3_ * bf2f(Wp[288 + u]) * K;
    } else if (c < 800) {
      int t2 = c - 480, u = t2 / 5, k = t2 - u * 5;
      float gk = (k == 0) ? g0 : ((k == 1) ? g1 : ((k == 2) ? g2 : ((k == 3) ? g3 : g4)));
      val = Y0[u] * gk * bf2f(Wp[128 + u]);
    } else {
      int t2 = c - 800, u = t2 / 5, k = t2 - u * 5;
      float xy = X1[u*3], xz = X1[u*3+1], xx = X1[u*3+2];
      float K;
      if (k == 0)      K = -B_ * (xy * ex + xx * ey);
      else if (k == 1) K = -B_ * (xy * ez + xz * ey);
      else if (k == 2) K =  A_ * (xy * ey + xx * ex - 2.f * xz * ez);
      else if (k == 3) K = -B_ * (xz * ex + xx * ez);
      else             K =  B_ * (xy * ey - xx * ex);
      val = SQ5_ * bf2f(Wp[256 + u]) * K;
    }
    acc[j] += val;
  }
}

// 4 nodes per block, ONE WAVE PER NODE, no block barriers. Sequential
// per-edge streams (wbuf/ed_s/src_s in sorted order), depth-2 reg prefetch,
// wave-synchronous LDS (s_waitcnt lgkmcnt(0) only).
// Per-wave LDS layout (floats, WREG=960):
//   Yb0 [0,160)  Yb1 [160,320)  Wq 2x320u16 [320,640)  Eb 2x16 [640,672)
//   Sv 64 ints [672,736)   -- DISJOINT (round-4 crash: Eb/Sv overlapped Wq)
#define WREG 960
__global__ __launch_bounds__(256) void node_agg(
    const float* __restrict__ y, const float* __restrict__ s,
    const float* __restrict__ attr,
    const float* __restrict__ ed_s, const int* __restrict__ src_s,
    const unsigned short* __restrict__ wbuf,
    const int* __restrict__ offs, const int* __restrict__ counts,
    const float* __restrict__ w0, const float* __restrict__ w1,
    const float* __restrict__ w2, float* __restrict__ out) {
  __shared__ __align__(16) float smem[4 * WREG];
  int tid = threadIdx.x, wid = tid >> 6, lane = tid & 63;
  int n = blockIdx.x * 4 + wid;
  float* R = smem + wid * WREG;
  float* Yb[2] = {R, R + 160};
  unsigned short* Wq = (unsigned short*)(R + 320);  // 2 slots x 320 u16 = [320,640)
  float* Eb = R + 640;                              // 2 x 16 f = [640,672)
  int* Sv = (int*)(R + 672);                        // 64 ints  = [672,736)
  int beg = offs[n], cnt = counts[n];

  float acc[15];
  #pragma unroll
  for (int j = 0; j < 15; ++j) acc[j] = 0.f;

#define ISSUE(py, pw, pe, gi, srcv)                                            \
  {                                                                            \
    if (lane < 40) py = ((const float4*)(y + (size_t)(srcv) * 160))[lane];     \
    if (lane >= 24) pw = ((const uint4*)(wbuf + (size_t)(gi) * 320))[lane-24]; \
    if (lane < 3)  pe = ((const float4*)(ed_s + (size_t)(gi) * 12))[lane];     \
  }
#define STAGE(sl, py, pw, pe)                                                  \
  {                                                                            \
    if (lane < 40) ((float4*)Yb[sl])[lane] = py;                               \
    if (lane >= 24) ((uint4*)(Wq + (sl) * 320))[lane - 24] = pw;               \
    if (lane < 3)  ((float4*)(Eb + (sl) * 16))[lane] = pe;                     \
  }
#define LWAIT __asm__ volatile("s_waitcnt lgkmcnt(0)" ::: "memory")

  for (int c0 = 0; c0 < cnt; c0 += 64) {
    int nc = min(64, cnt - c0);
    int g = beg + c0;
    if (lane < nc) Sv[lane] = src_s[g + lane];
    LWAIT;
    float4 py0, py1, pe0, pe1; uint4 pw0, pw1;
    if (nc > 0) { int sv = Sv[0]; ISSUE(py0, pw0, pe0, g + 0, sv); }
    if (nc > 1) { int sv = Sv[1]; ISSUE(py1, pw1, pe1, g + 1, sv); }
    int i = 0;
    while (i < nc) {
      STAGE(0, py0, pw0, pe0);
      if (i + 2 < nc) { int sv = Sv[i + 2]; ISSUE(py0, pw0, pe0, g + i + 2, sv); }
      LWAIT;
      edge_compute(Yb[0], Wq, Eb, lane, acc);
      ++i; if (i >= nc) break;
      STAGE(1, py1, pw1, pe1);
      if (i + 2 < nc) { int sv = Sv[i + 2]; ISSUE(py1, pw1, pe1, g + i + 2, sv); }
      LWAIT;
      edge_compute(Yb[1], Wq + 320, Eb + 16, lane, acc);
      ++i;
    }
  }

  // epilogue: wave-private m -> lin2 + combine (aliases dead pipeline LDS)
  LWAIT;
  #pragma unroll
  for (int j = 0; j < 15; ++j) R[lane + 64 * j] = acc[j] * QDEG;
  LWAIT;
  float a = attr[n];
  const float* srow = s + (size_t)n * 160;
  float* orow = out + (size_t)n * 320;
  #pragma unroll
  for (int jo = 0; jo < 5; ++jo) {
    int oc = lane + 64 * jo;
    orow[oc] = lin2_col(R, w0, w1, w2, srow, a, oc);
  }
#undef ISSUE
#undef STAGE
#undef LWAIT
}

extern "C" void kernel_launch(void* const* d_in, const int* in_sizes, int n_in,
                              void* d_out, int out_size, void* d_ws, size_t ws_size,
                              hipStream_t stream) {
  const float* node_input = (const float*)d_in[0];
  const float* node_attr  = (const float*)d_in[1];
  const int*   edge_src   = (const int*)d_in[2];
  const int*   edge_dst   = (const int*)d_in[3];
  const float* edge_attr  = (const float*)d_in[4];
  const float* ele        = (const float*)d_in[5];
  const float* sc_w0      = (const float*)d_in[6];
  const float* sc_w1      = (const float*)d_in[7];
  const float* l1_w0      = (const float*)d_in[8];
  const float* l1_w1      = (const float*)d_in[9];
  const float* fc_w0      = (const float*)d_in[10];
  const float* fc_w1      = (const float*)d_in[11];
  const float* l2_w0      = (const float*)d_in[12];
  const float* l2_w1      = (const float*)d_in[13];
  const float* l2_w2      = (const float*)d_in[14];
  float* out = (float*)d_out;

  char* base = (char*)d_ws;
  float* y              = (float*)(base);                       // 6.40 MB
  float* s              = (float*)(base + 6400000);             // 6.40 MB
  unsigned short* wbuf  = (unsigned short*)(base + 12800000);   // 102.4 MB
  float* ed_s           = (float*)(base + 115200000);           // 7.68 MB
  int* src_s            = (int*)(base + 122880000);             // 0.64 MB
  int* counts           = (int*)(base + 123520000);
  int* offs             = (int*)(base + 123560000);
  int* cur              = (int*)(base + 123600000);
  int* sorted           = (int*)(base + 123640000);             // 0.64 MB
  unsigned short* fc1p  = (unsigned short*)(base + 124280000);  // 40 KB

  hipLaunchKernelGGL(k_zero_int, dim3(40), dim3(256), 0, stream, counts, N_NODES);
  hipLaunchKernelGGL(k_hist, dim3((N_EDGES + 255) / 256), dim3(256), 0, stream,
                     edge_dst, counts);
  hipLaunchKernelGGL(k_scan, dim3(1), dim3(256), 0, stream, counts, offs, cur);
  hipLaunchKernelGGL(k_scatter, dim3((N_EDGES + 255) / 256), dim3(256), 0, stream,
                     edge_dst, cur, sorted);
  hipLaunchKernelGGL(node_pre, dim3(N_NODES * 160 / 256), dim3(256), 0, stream,
                     node_input, node_attr, sc_w0, sc_w1, l1_w0, l1_w1, s, y);
  hipLaunchKernelGGL(fc1p_build, dim3(80), dim3(256), 0, stream, fc_w1, fc1p);
  hipLaunchKernelGGL(w_gemm, dim3(N_EDGES / 64), dim3(256), 0, stream,
                     ele, fc_w0, sorted, edge_src, edge_attr, fc1p,
                     wbuf, ed_s, src_s);
  hipLaunchKernelGGL(node_agg, dim3(N_NODES / 4), dim3(256), 0, stream,
                     y, s, node_attr, ed_s, src_s, wbuf,
                     offs, counts, l2_w0, l2_w1, l2_w2, out);
}

// Round 6
// 345.237 us; speedup vs baseline: 3.0444x; 1.3998x over previous
//
#include <hip/hip_runtime.h>
#include <cstddef>
#include <cstdint>

#define N_NODES 10000
#define N_EDGES 160000

// ---- constants ----
#define RS8    0.35355339059327373f   // 1/sqrt(8)
#define RS32   0.17677669529663687f   // 1/sqrt(32)
#define RS96   0.10206207261596575f   // 1/sqrt(96)
#define RS128  0.08838834764831845f   // 1/sqrt(128)
#define RS3    0.5773502691896258f    // 1/sqrt(3)
#define SQ3_   1.7320508075688772f
#define SQ5_   2.23606797749979f
#define A_     0.18257418583505536f   // 1/sqrt(30)
#define B_     0.31622776601683794f   // 1/sqrt(10)
#define SILU_C_ 1.6765208f
#define CS_    0.3826834323650898f    // sin(pi/8)
#define CX_    0.9238795325112867f    // cos(pi/8)
#define QDEG   0.25f                  // 1/sqrt(16)

typedef __attribute__((ext_vector_type(8))) short bf16x8;
typedef __attribute__((ext_vector_type(4))) float f32x4;

__device__ inline float bf2f(unsigned v) {
  union { unsigned u; float f; } c; c.u = v << 16; return c.f;
}
__device__ inline unsigned short f2bf(float f) {
  union { float f; unsigned u; } c; c.f = f;
  unsigned r = c.u + 0x7fff + ((c.u >> 16) & 1);
  return (unsigned short)(r >> 16);
}

__global__ void k_zero_int(int* __restrict__ p, int n) {
  int i = blockIdx.x * blockDim.x + threadIdx.x;
  if (i < n) p[i] = 0;
}

__global__ void k_hist(const int* __restrict__ edst, int* __restrict__ counts) {
  int e = blockIdx.x * blockDim.x + threadIdx.x;
  if (e < N_EDGES) atomicAdd(&counts[edst[e]], 1);
}

// exclusive scan of counts -> offs/cur; ALSO degree histogram (LDS) and
// descending-degree exclusive scan -> dcur (single block, no extra launches).
__global__ __launch_bounds__(256) void k_scan(const int* __restrict__ counts,
                                              int* __restrict__ offs,
                                              int* __restrict__ cur,
                                              int* __restrict__ dcur) {
  __shared__ int ps[256];
  __shared__ int dbin[256];
  int t = threadIdx.x;
  dbin[t] = 0;
  int base = t * 40;
  int sum = 0;
  for (int i = 0; i < 40; ++i) {
    int idx = base + i;
    if (idx < N_NODES) sum += counts[idx];
  }
  ps[t] = sum;
  __syncthreads();
  for (int off = 1; off < 256; off <<= 1) {
    int v = (t >= off) ? ps[t - off] : 0;
    __syncthreads();
    ps[t] += v;
    __syncthreads();
  }
  int run = (t == 0) ? 0 : ps[t - 1];
  for (int i = 0; i < 40; ++i) {
    int idx = base + i;
    if (idx < N_NODES) {
      int c = counts[idx];
      offs[idx] = run; cur[idx] = run;
      run += c;
      atomicAdd(&dbin[c < 255 ? c : 255], 1);
    }
  }
  __syncthreads();
  // descending-order exclusive scan of degree bins
  int rb = 255 - t;
  int v = dbin[rb];
  __syncthreads();
  ps[t] = v;
  __syncthreads();
  for (int off = 1; off < 256; off <<= 1) {
    int u = (t >= off) ? ps[t - off] : 0;
    __syncthreads();
    ps[t] += u;
    __syncthreads();
  }
  dcur[rb] = ps[t] - v;
}

// edge scatter (sorted-by-dst) + node scatter (descending-degree order)
__global__ void k_scatter(const int* __restrict__ edst, int* __restrict__ cur,
                          int* __restrict__ sorted, const int* __restrict__ counts,
                          int* __restrict__ dcur, int* __restrict__ order) {
  int e = blockIdx.x * blockDim.x + threadIdx.x;
  if (e < N_EDGES) {
    int d = edst[e];
    int p = atomicAdd(&cur[d], 1);
    sorted[p] = e;
  }
  if (e < N_NODES) {
    int b = counts[e]; b = b < 255 ? b : 255;
    int p = atomicAdd(&dcur[b], 1);
    order[p] = e;
  }
}

// s[n][0:160], y[n][0:160]
__global__ void node_pre(const float* __restrict__ xin, const float* __restrict__ attr,
                         const float* __restrict__ sc_w0, const float* __restrict__ sc_w1,
                         const float* __restrict__ l1_w0, const float* __restrict__ l1_w1,
                         float* __restrict__ s, float* __restrict__ y) {
  int idx = blockIdx.x * blockDim.x + threadIdx.x;
  int n = idx / 160, c = idx - n * 160;
  const float* xr = xin + (size_t)n * 160;
  float a = attr[n];
  float sv, yv;
  if (c < 64) {
    float s_ = 0.f, y_ = 0.f;
    #pragma unroll 8
    for (int u = 0; u < 64; ++u) {
      float x = xr[u];
      s_ += x * sc_w0[u * 64 + c];
      y_ += x * l1_w0[u * 64 + c];
    }
    sv = s_ * a * 0.125f; yv = y_ * a * 0.125f;
  } else {
    int t = c - 64; int v = t / 3, i = t - v * 3;
    float s_ = 0.f, y_ = 0.f;
    #pragma unroll 8
    for (int u = 0; u < 32; ++u) {
      float x = xr[64 + u * 3 + i];
      s_ += x * sc_w1[u * 32 + v];
      y_ += x * l1_w1[u * 32 + v];
    }
    sv = s_ * a * RS32; yv = y_ * a * RS32;
  }
  s[idx] = sv; y[idx] = yv;
}

// fc1 (64x320 f32) -> bf16 packed in MFMA B-fragment order
__global__ void fc1p_build(const float* __restrict__ fc1,
                           unsigned short* __restrict__ fc1p) {
  int i = blockIdx.x * blockDim.x + threadIdx.x;
  if (i >= 20480) return;
  int j = i & 7, q = (i >> 3) & 3, n = (i >> 5) & 15, kq = (i >> 9) & 1, t = i >> 10;
  int k = kq * 32 + q * 8 + j;
  fc1p[i] = f2bf(fc1[k * 320 + t * 16 + n]);
}

// MFMA bf16 radial GEMM over 64 SORTED edges per block; writes w rows at the
// sorted position + permuted SH stream (ed_s, stride 12; slot 9 holds src id).
__global__ __launch_bounds__(256) void w_gemm(
    const float* __restrict__ ele, const float* __restrict__ fc0,
    const int* __restrict__ sorted, const int* __restrict__ esrc,
    const float* __restrict__ eattr, const unsigned short* __restrict__ fc1p,
    unsigned short* __restrict__ wout, float* __restrict__ ed_s) {
  __shared__ int sh_ids[64];
  __shared__ __align__(16) float sh_ele[64][8];
  __shared__ __align__(16) unsigned short sh_h[64 * 72];  // 72-stride pad
  int t = threadIdx.x;
  int eb = blockIdx.x * 64;

  if (t < 64) sh_ids[t] = sorted[eb + t];
  __syncthreads();
  if (t < 128) {
    int e = t >> 1, hh = t & 1;
    ((float4*)&sh_ele[e][0])[hh] = ((const float4*)(ele + (size_t)sh_ids[e] * 8))[hh];
  }
  for (int i = t; i < 576; i += 256) {
    int e = i / 9, k = i - e * 9;
    ed_s[(size_t)(eb + e) * 12 + k] = eattr[(size_t)sh_ids[e] * 9 + k];
  }
  if (t < 64) ((int*)ed_s)[(size_t)(eb + t) * 12 + 9] = esrc[sh_ids[t]];
  __syncthreads();
  // h = silu(ele@fc0/sqrt8)*SILU_C -> bf16, A-layout [edge][k], stride 72
  #pragma unroll
  for (int ii = 0; ii < 16; ++ii) {
    int idx = t + ii * 256;
    int e = idx >> 6, k = idx & 63;
    float acc = 0.f;
    #pragma unroll
    for (int m = 0; m < 8; ++m) acc += sh_ele[e][m] * fc0[m * 64 + k];
    acc *= RS8;
    float hv = SILU_C_ * acc / (1.f + __expf(-acc));
    sh_h[e * 72 + k] = f2bf(hv);
  }
  __syncthreads();

  int wv = t >> 6, lane = t & 63;
  int m0 = wv * 16;
  int mrow = lane & 15, quad = lane >> 4;
  const bf16x8* A0 = (const bf16x8*)(sh_h + (m0 + mrow) * 72 + quad * 8);
  const bf16x8* A1 = (const bf16x8*)(sh_h + (m0 + mrow) * 72 + 32 + quad * 8);
  bf16x8 a0 = *A0, a1 = *A1;
  #pragma unroll 4
  for (int t20 = 0; t20 < 20; ++t20) {
    f32x4 acc = {0.f, 0.f, 0.f, 0.f};
    bf16x8 b0 = *(const bf16x8*)(fc1p + ((size_t)((t20 * 2 + 0) * 16 + mrow) * 4 + quad) * 8);
    bf16x8 b1 = *(const bf16x8*)(fc1p + ((size_t)((t20 * 2 + 1) * 16 + mrow) * 4 + quad) * 8);
    acc = __builtin_amdgcn_mfma_f32_16x16x32_bf16(a0, b0, acc, 0, 0, 0);
    acc = __builtin_amdgcn_mfma_f32_16x16x32_bf16(a1, b1, acc, 0, 0, 0);
    #pragma unroll
    for (int r = 0; r < 4; ++r) {
      int row = m0 + quad * 4 + r;
      wout[(size_t)(eb + row) * 320 + t20 * 16 + mrow] = f2bf(acc[r] * 0.125f);
    }
  }
}

__device__ inline float lin2_col(const float* __restrict__ sm,
                                 const float* __restrict__ w0,
                                 const float* __restrict__ w1,
                                 const float* __restrict__ w2,
                                 const float* __restrict__ srow,
                                 float a, int oc) {
  if (oc < 64) {
    float o = 0.f;
    #pragma unroll 8
    for (int u = 0; u < 96; ++u) o += sm[u] * w0[u * 64 + oc];
    return CS_ * srow[oc] + CX_ * (o * a * RS96);
  } else if (oc < 160) {
    int t = oc - 64, v = t / 3, i = t - v * 3;
    float o = 0.f;
    #pragma unroll 8
    for (int u = 0; u < 128; ++u) o += sm[96 + u * 3 + i] * w1[u * 32 + v];
    return CS_ * srow[oc] + CX_ * (o * a * RS128);
  } else {
    int t = oc - 160, v = t / 5, k = t - v * 5;
    float o = 0.f;
    #pragma unroll 8
    for (int u = 0; u < 96; ++u) o += sm[480 + u * 5 + k] * w2[u * 32 + v];
    return o * a * RS96;
  }
}

// One wave per node (degree-ordered), u-major lane mapping: every operand is
// loaded from global DIRECTLY into the lane that needs it — no LDS in the
// per-edge loop. lane=u for scalar channels; lane&31=u' for vector channels
// (upper half duplicates vector work; only lanes<32 write it back).
// 21 accumulators/lane; depth-2 register prefetch; src embedded in ed_s[.,9].
#define WREG 960
__global__ __launch_bounds__(256) void node_agg(
    const float* __restrict__ y, const float* __restrict__ s,
    const float* __restrict__ attr, const float* __restrict__ ed_s,
    const unsigned short* __restrict__ wbuf,
    const int* __restrict__ offs, const int* __restrict__ counts,
    const int* __restrict__ order,
    const float* __restrict__ w0, const float* __restrict__ w1,
    const float* __restrict__ w2, float* __restrict__ out) {
  __shared__ __align__(16) float smem[4 * WREG];
  int tid = threadIdx.x, wid = tid >> 6, lane = tid & 63, l31 = lane & 31;
  int n = order[blockIdx.x * 4 + wid];
  float* R = smem + wid * WREG;
  int beg = offs[n], cnt = counts[n];

  float aK0 = 0.f, aK2x = 0.f, aK2y = 0.f, aK2z = 0.f;
  float aK5a = 0.f, aK5b = 0.f, aK5c = 0.f, aK5d = 0.f, aK5e = 0.f;
  float aK1 = 0.f, aK3x = 0.f, aK3y = 0.f, aK3z = 0.f;
  float aK4x = 0.f, aK4y = 0.f, aK4z = 0.f;
  float aK6a = 0.f, aK6b = 0.f, aK6c = 0.f, aK6d = 0.f, aK6e = 0.f;

  float Ya, X0a, X1a, X2a, Yb, X0b, X1b, X2b;
  unsigned wAa, wBa, wCa, wDa, wEa, wFa, wGa;
  unsigned wAb, wBb, wCb, wDb, wEb, wFb, wGb;
  float4 P0a, P1a, P2a, P0b, P1b, P2b;

#define ISSUE(S, gg, sv)                                                       \
  {                                                                            \
    const float* yb = y + (size_t)(sv) * 160;                                  \
    Y##S = yb[lane];                                                           \
    X0##S = yb[64 + 3 * l31]; X1##S = yb[65 + 3 * l31]; X2##S = yb[66 + 3 * l31]; \
    const unsigned short* wb = wbuf + (size_t)(gg) * 320;                      \
    wA##S = wb[lane]; wB##S = wb[64 + lane]; wC##S = wb[128 + lane];           \
    wD##S = wb[192 + l31]; wE##S = wb[224 + l31];                              \
    wF##S = wb[256 + l31]; wG##S = wb[288 + l31];                              \
    const float4* ep = (const float4*)(ed_s + (size_t)(gg) * 12);              \
    P0##S = ep[0]; P1##S = ep[1]; P2##S = ep[2];                               \
  }

#define COMPUTE(S)                                                             \
  {                                                                            \
    float e0 = P0##S.x, ey = P0##S.y, ez = P0##S.z, ex = P0##S.w;              \
    float q0 = P1##S.x, q1 = P1##S.y, q2 = P1##S.z, q3 = P1##S.w;              \
    float q4 = P2##S.x;                                                        \
    float Yv = Y##S, x0 = X0##S, x1 = X1##S, x2 = X2##S;                       \
    float vA = bf2f(wA##S), vB = bf2f(wB##S), vC = bf2f(wC##S);                \
    float vD = bf2f(wD##S), vE = bf2f(wE##S), vF = bf2f(wF##S), vG = bf2f(wG##S); \
    aK0 += Yv * e0 * vA;                                                       \
    float tB = Yv * vB; aK2x += tB * ey; aK2y += tB * ez; aK2z += tB * ex;     \
    float tC = Yv * vC;                                                        \
    aK5a += tC * q0; aK5b += tC * q1; aK5c += tC * q2;                         \
    aK5d += tC * q3; aK5e += tC * q4;                                          \
    float t1 = x0 * ey + x1 * ez + x2 * ex; aK1 += (RS3 * vE) * t1;            \
    float s3 = e0 * vD; aK3x += x0 * s3; aK3y += x1 * s3; aK3z += x2 * s3;     \
    float s4 = SQ3_ * vG;                                                      \
    aK4x += s4 * (B_ * (x2 * q0 + x1 * q1 - x0 * q4) - A_ * x0 * q2);          \
    aK4y += s4 * (B_ * (x0 * q1 + x2 * q3) + 2.f * A_ * x1 * q2);              \
    aK4z += s4 * (B_ * (x0 * q0 + x1 * q3 + x2 * q4) - A_ * x2 * q2);          \
    float s6 = SQ5_ * vF;                                                      \
    aK6a += s6 * (-B_ * (x0 * ex + x2 * ey));                                  \
    aK6b += s6 * (-B_ * (x0 * ez + x1 * ey));                                  \
    aK6c += s6 * ( A_ * (x0 * ey + x2 * ex - 2.f * x1 * ez));                  \
    aK6d += s6 * (-B_ * (x1 * ex + x2 * ez));                                  \
    aK6e += s6 * ( B_ * (x0 * ey - x2 * ex));                                  \
  }
#define SRC_OF(gg) (((const int*)ed_s)[(size_t)(gg) * 12 + 9])
#define LWAIT __asm__ volatile("s_waitcnt lgkmcnt(0)" ::: "memory")

  if (cnt > 0) {
    int sA = SRC_OF(beg);
    ISSUE(a, beg, sA);
    int s_next = (cnt > 1) ? SRC_OF(beg + 1) : 0;
    int i = 0;
    while (true) {
      int s_next2 = (i + 2 < cnt) ? SRC_OF(beg + i + 2) : 0;
      if (i + 1 < cnt) ISSUE(b, beg + i + 1, s_next);
      COMPUTE(a);
      ++i; if (i >= cnt) break;
      s_next = s_next2;
      s_next2 = (i + 2 < cnt) ? SRC_OF(beg + i + 2) : 0;
      if (i + 1 < cnt) ISSUE(a, beg + i + 1, s_next);
      COMPUTE(b);
      ++i; if (i >= cnt) break;
      s_next = s_next2;
    }
  }

  // epilogue: distributed accs -> wave-private sh_m -> lin2 + combine
  R[lane]            = aK0  * QDEG;
  R[96 + 3 * lane]   = aK2x * QDEG;
  R[97 + 3 * lane]   = aK2y * QDEG;
  R[98 + 3 * lane]   = aK2z * QDEG;
  R[480 + 5 * lane]  = aK5a * QDEG;
  R[481 + 5 * lane]  = aK5b * QDEG;
  R[482 + 5 * lane]  = aK5c * QDEG;
  R[483 + 5 * lane]  = aK5d * QDEG;
  R[484 + 5 * lane]  = aK5e * QDEG;
  if (lane < 32) {
    R[64 + lane]       = aK1  * QDEG;
    R[288 + 3 * lane]  = aK3x * QDEG;
    R[289 + 3 * lane]  = aK3y * QDEG;
    R[290 + 3 * lane]  = aK3z * QDEG;
    R[384 + 3 * lane]  = aK4x * QDEG;
    R[385 + 3 * lane]  = aK4y * QDEG;
    R[386 + 3 * lane]  = aK4z * QDEG;
    R[800 + 5 * lane]  = aK6a * QDEG;
    R[801 + 5 * lane]  = aK6b * QDEG;
    R[802 + 5 * lane]  = aK6c * QDEG;
    R[803 + 5 * lane]  = aK6d * QDEG;
    R[804 + 5 * lane]  = aK6e * QDEG;
  }
  LWAIT;
  float a = attr[n];
  const float* srow = s + (size_t)n * 160;
  float* orow = out + (size_t)n * 320;
  #pragma unroll
  for (int jo = 0; jo < 5; ++jo) {
    int oc = lane + 64 * jo;
    orow[oc] = lin2_col(R, w0, w1, w2, srow, a, oc);
  }
#undef ISSUE
#undef COMPUTE
#undef SRC_OF
#undef LWAIT
}

extern "C" void kernel_launch(void* const* d_in, const int* in_sizes, int n_in,
                              void* d_out, int out_size, void* d_ws, size_t ws_size,
                              hipStream_t stream) {
  const float* node_input = (const float*)d_in[0];
  const float* node_attr  = (const float*)d_in[1];
  const int*   edge_src   = (const int*)d_in[2];
  const int*   edge_dst   = (const int*)d_in[3];
  const float* edge_attr  = (const float*)d_in[4];
  const float* ele        = (const float*)d_in[5];
  const float* sc_w0      = (const float*)d_in[6];
  const float* sc_w1      = (const float*)d_in[7];
  const float* l1_w0      = (const float*)d_in[8];
  const float* l1_w1      = (const float*)d_in[9];
  const float* fc_w0      = (const float*)d_in[10];
  const float* fc_w1      = (const float*)d_in[11];
  const float* l2_w0      = (const float*)d_in[12];
  const float* l2_w1      = (const float*)d_in[13];
  const float* l2_w2      = (const float*)d_in[14];
  float* out = (float*)d_out;

  char* base = (char*)d_ws;
  float* y              = (float*)(base);                       // 6.40 MB
  float* s              = (float*)(base + 6400000);             // 6.40 MB
  unsigned short* wbuf  = (unsigned short*)(base + 12800000);   // 102.4 MB
  float* ed_s           = (float*)(base + 115200000);           // 7.68 MB (SH + src)
  int* counts           = (int*)(base + 122880000);             // 40 KB
  int* offs             = (int*)(base + 122920000);
  int* cur              = (int*)(base + 122960000);
  int* sorted           = (int*)(base + 123000000);             // 0.64 MB
  unsigned short* fc1p  = (unsigned short*)(base + 123640000);  // 40 KB
  int* dcur             = (int*)(base + 123680960);             // 1 KB
  int* order            = (int*)(base + 123682048);             // 40 KB

  hipLaunchKernelGGL(k_zero_int, dim3(40), dim3(256), 0, stream, counts, N_NODES);
  hipLaunchKernelGGL(k_hist, dim3((N_EDGES + 255) / 256), dim3(256), 0, stream,
                     edge_dst, counts);
  hipLaunchKernelGGL(k_scan, dim3(1), dim3(256), 0, stream, counts, offs, cur, dcur);
  hipLaunchKernelGGL(k_scatter, dim3((N_EDGES + 255) / 256), dim3(256), 0, stream,
                     edge_dst, cur, sorted, counts, dcur, order);
  hipLaunchKernelGGL(node_pre, dim3(N_NODES * 160 / 256), dim3(256), 0, stream,
                     node_input, node_attr, sc_w0, sc_w1, l1_w0, l1_w1, s, y);
  hipLaunchKernelGGL(fc1p_build, dim3(80), dim3(256), 0, stream, fc_w1, fc1p);
  hipLaunchKernelGGL(w_gemm, dim3(N_EDGES / 64), dim3(256), 0, stream,
                     ele, fc_w0, sorted, edge_src, edge_attr, fc1p, wbuf, ed_s);
  hipLaunchKernelGGL(node_agg, dim3(N_NODES / 4), dim3(256), 0, stream,
                     y, s, node_attr, ed_s, wbuf,
                     offs, counts, order, l2_w0, l2_w1, l2_w2, out);
}